// Round 6
// baseline (345.116 us; speedup 1.0000x reference)
//
#include <hip/hip_runtime.h>
#include <math.h>

// Problem constants
#define NCASES   16
#define NPTS_BIG 65536
#define F1       512
#define OUT_B    4096

typedef __attribute__((ext_vector_type(8))) short  short8;   // 8 bf16 = 4 VGPR (MFMA A/B frag)
typedef __attribute__((ext_vector_type(4))) float  floatx4;  // MFMA C/D frag
typedef unsigned short ush;

__device__ __forceinline__ float silu_f(float x) {
    return x * __builtin_amdgcn_rcpf(1.0f + __expf(-x));
}

// RNE fp32->bf16 left in bits [31:16]  (used in one-time prep only)
__device__ __forceinline__ unsigned f2bf_hi(float x) {
    unsigned u = __float_as_uint(x);
    return u + 0x7FFFu + ((u >> 16) & 1u);
}
__device__ __forceinline__ ush f2bf(float x) {
    return (ush)(f2bf_hi(x) >> 16);
}
// RTZ pack: two f32 -> two bf16 in one v_perm (truncate mantissa; hot-loop path).
__device__ __forceinline__ unsigned pk2bf_rtz(float lo, float hi) {
    return __builtin_amdgcn_perm(__float_as_uint(hi), __float_as_uint(lo), 0x07060302u);
}

// Monotone float -> uint mapping (handles negatives) for atomicMax argmax.
__device__ __forceinline__ unsigned enc_f(float x) {
    unsigned u = __float_as_uint(x);
    return (u & 0x80000000u) ? ~u : (u | 0x80000000u);
}
__device__ __forceinline__ float dec_f(unsigned e) {
    unsigned u = (e & 0x80000000u) ? (e ^ 0x80000000u) : ~e;
    return __uint_as_float(u);
}

// force value to SGPR
__device__ __forceinline__ float sgpr_f(float x) {
    return __uint_as_float(__builtin_amdgcn_readfirstlane(__float_as_uint(x)));
}

// Pre-swizzle W11/W12 into MFMA B-fragment order (bf16, RNE) + zero argmax buffers.
// B-layout for 16x16x32: B[k = KT*32 + (lane>>4)*8 + j][n = lane&15].
// BcWs: [w(8)][NT(4)][KT(4)][lane(64)][j(8)]  (W12, 128 KB)
// BbWs: [w(8)][KT(2)][lane(64)][j(8)]         (W11, 16 KB)
__global__ void k_prep(const float* __restrict__ W11, const float* __restrict__ W12,
                       ush* __restrict__ BbWs, ush* __restrict__ BcWs,
                       unsigned long long* __restrict__ argBufs)
{
    int i = blockIdx.x * 256 + threadIdx.x;   // 65536 threads
    if (i < 16384) argBufs[i] = 0ull;         // argBuf + argBuf2
    {
        int j = i & 7, l = (i >> 3) & 63, t = i >> 9;     // t = w*16 + NT*4 + KT
        int KT = t & 3, NT = (t >> 2) & 3, w = t >> 4;
        int k = KT * 32 + (l >> 4) * 8 + j;
        int f = w * 64 + NT * 16 + (l & 15);
        BcWs[i] = f2bf(W12[(size_t)k * 512 + f]);
    }
    if (i < 8192) {
        int j = i & 7, l = (i >> 3) & 63, t = i >> 9;     // t = w*2 + KT
        int KT = t & 1, w = t >> 1;
        int k = KT * 32 + (l >> 4) * 8 + j;
        int f = w * 16 + (l & 15);
        BbWs[i] = f2bf(W11[(size_t)k * 128 + f]);
    }
}

// Fused mlp1 + per-feature argmax of PRE-ACTIVATION (silu monotone for x>=-1.278,
// silu(x)<0 for x<0, per-feature max pre-act > 0 w.o.p. -> argmax silu(z) == argmax z).
// b12 added after the max; silu applied downstream (k_head).
//
// OCCUPANCY RESTRUCTURE (this round): R0-R5 showed phase-1 pinned at 164-167us
// across 3 schedules; diagnosis = latency-bound at 4 waves/SIMD (regs 60+64 AGPR
// Bc).  Fix: NO resident Bc.  W12 B-frags streamed from global (BcWs 128KB =
// L2-resident) in NT-HALVES (8 frags = 32 VGPR), C-stage runs per CHUNK-PAIR so
// each Bg load serves 2 chunks (L2 demand ~8 TB/s aggregate << 34.5).  Each half
// re-reads h1 A-frags (LDS x2 -- traded against occupancy).  Bb also streamed.
// Region structure per pair (hazards all >=1-barrier separated, h0/h1 dbuf):
//   [ B(2k):h0[0]->h1[0] | bar | B(2k+1):h0[1]->h1[1] | bar |
//     C(2k,2k+1) + A(2k+2)->h0[0] + A(2k+3)->h0[1] | bar ]
// __launch_bounds__(512,6): cap regs ~85 -> 3 blocks/CU (LDS 53248*3 <= 160K).
template<bool GATHER>
__global__ __launch_bounds__(512, 6)
void k_mlp1_argmax(const float* __restrict__ pts, int nPts, int chunksPerBlock,
                   const unsigned long long* __restrict__ gatherIdx,
                   const float* __restrict__ W10, const float* __restrict__ b10,
                   const float* __restrict__ b11, const float* __restrict__ b12,
                   const ush* __restrict__ BbWs,
                   const ush* __restrict__ BcWs,
                   unsigned long long* __restrict__ argOut)
{
    const int c   = blockIdx.y;
    const int tid = threadIdx.x;
    const int w   = tid >> 6;   // wave 0..7
    const int l   = tid & 63;   // lane
    const int lm  = l & 15;     // m/n within 16x16 tile
    const int q   = l >> 4;     // quad

    __shared__ __align__(16) ush s_h0[2][64][72];   // bf16, stride 144B, dbuf
    __shared__ __align__(16) ush s_h1[2][64][136];  // bf16, stride 272B, dbuf
    // 53248 B LDS exactly -> 3 blocks/CU at 160 KiB

    const int wf = __builtin_amdgcn_readfirstlane(w);   // wave-uniform

    // stage-A weights in SGPRs (no LDS, no per-chunk reloads)
    float wA0[8], wA1[8], wA2[8], bA[8];
    #pragma unroll
    for (int j = 0; j < 8; ++j) {
        wA0[j] = sgpr_f(W10[  0 + wf * 8 + j]);
        wA1[j] = sgpr_f(W10[ 64 + wf * 8 + j]);
        wA2[j] = sgpr_f(W10[128 + wf * 8 + j]);
        bA[j]  = sgpr_f(b10[       wf * 8 + j]);
    }

    const float bias11 = b11[wf * 16 + lm];

    float bestv[4];
    #pragma unroll
    for (int NT = 0; NT < 4; ++NT) bestv[NT] = -INFINITY;

    const float* cpts = pts + (size_t)c * nPts * 3;
    const ush* BbG = BbWs + (size_t)((wf * 2) * 64 + l) * 8;       // wave's W11 frags
    const ush* BcG = BcWs + (size_t)((wf * 16) * 64 + l) * 8;      // wave's W12 frags

    // ---- helpers ----
    auto ldpt = [&](int ch, float& x, float& y, float& z) {
        const int pbase = (blockIdx.x * chunksPerBlock + ch) * 64;
        if (GATHER) {
            unsigned gi = ~(unsigned)(gatherIdx[(size_t)c * 512 + pbase + l] & 0xFFFFFFFFull);
            const float* sp = cpts + (size_t)gi * 3;
            x = sp[0]; y = sp[1]; z = sp[2];
        } else {
            const float* sp = cpts + (size_t)(pbase + l) * 3;
            x = sp[0]; y = sp[1]; z = sp[2];
        }
    };
    // stage A: h0[p][64][64] = silu(pts @ W10 + b10); lane = point, wave = 8 feats
    auto stageA = [&](int p, float x, float y, float z) {
        float v[8];
        #pragma unroll
        for (int j = 0; j < 8; ++j) {
            float t = fmaf(z, wA2[j], bA[j]);
            t = fmaf(y, wA1[j], t);
            t = fmaf(x, wA0[j], t);
            v[j] = silu_f(t);
        }
        uint4 hv = { pk2bf_rtz(v[0], v[1]), pk2bf_rtz(v[2], v[3]),
                     pk2bf_rtz(v[4], v[5]), pk2bf_rtz(v[6], v[7]) };
        *(uint4*)&s_h0[p][l][wf * 8] = hv;   // 16B aligned
    };
    // stage B: h1[p] = silu(h0[p] @ W11 + b11); Bb streamed from L2 (2 x b128)
    auto stageB = [&](int p) {
        short8 Bb0 = *(const short8*)(BbG);
        short8 Bb1 = *(const short8*)(BbG + 512);
        #pragma unroll
        for (int MT = 0; MT < 4; ++MT) {
            short8 a0 = *(const short8*)&s_h0[p][MT * 16 + lm][q * 8];        // A[m=lm][k=q*8+j]
            short8 a1 = *(const short8*)&s_h0[p][MT * 16 + lm][32 + q * 8];
            floatx4 acc = {bias11, bias11, bias11, bias11};
            acc = __builtin_amdgcn_mfma_f32_16x16x32_bf16(a0, Bb0, acc, 0, 0, 0);
            acc = __builtin_amdgcn_mfma_f32_16x16x32_bf16(a1, Bb1, acc, 0, 0, 0);
            #pragma unroll
            for (int r = 0; r < 4; ++r) {  // C/D: row = q*4+r (point), col = lm (feature)
                unsigned uv = __float_as_uint(silu_f(acc[r]));   // RTZ bf16: raw hi-half
                s_h1[p][MT * 16 + q * 4 + r][wf * 16 + lm] = (ush)(uv >> 16);
            }
        }
    };
    // C for one chunk's MT row-tile against one Bg half (2 NT tiles)
    auto cChunk = [&](const ush (*H1)[136], int cb0, const short8* Bg, float* bv, int MT) {
        short8 a[4];
        #pragma unroll
        for (int KT = 0; KT < 4; ++KT)
            a[KT] = *(const short8*)&H1[MT * 16 + lm][KT * 32 + q * 8];
        const int cbM = cb0 - (MT << 2);
        #pragma unroll
        for (int NTl = 0; NTl < 2; ++NTl) {
            floatx4 acc = {0.f, 0.f, 0.f, 0.f};
            #pragma unroll
            for (int KT = 0; KT < 4; ++KT)
                acc = __builtin_amdgcn_mfma_f32_16x16x32_bf16(a[KT], Bg[NTl * 4 + KT], acc, 0, 0, 0);
            // code-in-mantissa: (bits & ~127) | code; decode exact at flush
            float x0 = __uint_as_float((__float_as_uint(acc[0]) & 0xFFFFFF80u) | (unsigned)(cbM));
            float x1 = __uint_as_float((__float_as_uint(acc[1]) & 0xFFFFFF80u) | (unsigned)(cbM - 1));
            float x2 = __uint_as_float((__float_as_uint(acc[2]) & 0xFFFFFF80u) | (unsigned)(cbM - 2));
            float x3 = __uint_as_float((__float_as_uint(acc[3]) & 0xFFFFFF80u) | (unsigned)(cbM - 3));
            float t0 = fmaxf(fmaxf(x0, x1), x2);
            bv[NTl] = fmaxf(fmaxf(t0, x3), bv[NTl]);
        }
    };
    // one NT-half of C over a chunk pair: stream 8 W12 frags (32 VGPR), use twice
    auto cHalf = [&](int chA, bool haveB, int halfIdx, float* bv) {
        short8 Bg[8];
        const ush* gb = BcG + (size_t)halfIdx * 8 * 512;
        #pragma unroll
        for (int t = 0; t < 8; ++t)
            Bg[t] = *(const short8*)(gb + (size_t)t * 512);
        const int cbA = 127 - (chA << 4);
        const int cbB = 127 - ((chA + 1) << 4);
        #pragma unroll 1                     // bound live set (R3 spill lesson)
        for (int MT = 0; MT < 4; ++MT) {
            cChunk(s_h1[0], cbA, Bg, bv, MT);
            if (haveB) cChunk(s_h1[1], cbB, Bg, bv, MT);
        }
    };

    // ---- prologue: A(0) [+ A(1)] ----
    {
        float x0, y0, z0, x1, y1, z1;
        const bool h1c = (chunksPerBlock > 1);
        ldpt(0, x0, y0, z0);
        if (h1c) ldpt(1, x1, y1, z1);
        stageA(0, x0, y0, z0);
        if (h1c) stageA(1, x1, y1, z1);
    }
    __syncthreads();

    // ---- main: chunk pairs ----
    const int P = chunksPerBlock >> 1;
    for (int k = 0; k < P; ++k) {
        const int c0 = 2 * k;
        stageB(0);                 // B(c0): h0[0] -> h1[0]
        __syncthreads();
        stageB(1);                 // B(c0+1): h0[1] -> h1[1]
        __syncthreads();
        // region III: C(pair) + stage A for next pair (pt loads issued early)
        float ax, ay, az, bx, by, bz;
        const bool hA = (c0 + 2 < chunksPerBlock);
        const bool hB = (c0 + 3 < chunksPerBlock);
        if (hA) ldpt(c0 + 2, ax, ay, az);
        if (hB) ldpt(c0 + 3, bx, by, bz);
        cHalf(c0, true, 0, &bestv[0]);
        __builtin_amdgcn_sched_barrier(0);   // keep Bg halves' live ranges disjoint
        cHalf(c0, true, 1, &bestv[2]);
        if (hA) stageA(0, ax, ay, az);
        if (hB) stageA(1, bx, by, bz);
        __syncthreads();
    }
    // ---- odd tail (phase-2: chunksPerBlock == 1) ----
    if (chunksPerBlock & 1) {
        const int c0 = chunksPerBlock - 1;   // staged in h0[0]
        stageB(0);
        __syncthreads();
        cHalf(c0, false, 0, &bestv[0]);
        __builtin_amdgcn_sched_barrier(0);
        cHalf(c0, false, 1, &bestv[2]);
    }

    // ---- flush: decode code, strip it, combine quads via shfl, add b12, atomicMax ----
    #pragma unroll
    for (int NT = 0; NT < 4; ++NT) {
        unsigned u = __float_as_uint(bestv[NT]);
        int t = 127 - (int)(u & 127u);            // = ch<<4 | MT<<2 | r  (exact)
        unsigned idx = (unsigned)((blockIdx.x * chunksPerBlock + (t >> 4)) * 64
                                  + ((t >> 2) & 3) * 16 + q * 4 + (t & 3));
        float v = __uint_as_float(u & 0xFFFFFF80u) + b12[wf * 64 + NT * 16 + lm];
        #pragma unroll
        for (int m = 16; m <= 32; m <<= 1) {
            float    vo = __shfl_xor(v, m, 64);
            unsigned io = __shfl_xor(idx, m, 64);
            if (vo > v || (vo == v && io < idx)) { v = vo; idx = io; }
        }
        if (q == 0) {
            unsigned long long key = ((unsigned long long)enc_f(v) << 32)
                                   | (unsigned long long)(~idx);
            atomicMax(&argOut[(size_t)c * 512 + wf * 64 + NT * 16 + lm], key);
        }
    }
}

// Head: latent0 = silu(decoded max pre-act) -> silu(@W20+b20) -> @W21+b21. One block/case.
__global__ __launch_bounds__(256)
void k_head(const unsigned long long* __restrict__ argBuf2,
            const float* __restrict__ W20, const float* __restrict__ b20,
            const float* __restrict__ W21, const float* __restrict__ b21,
            float* __restrict__ latent)
{
    const int c = blockIdx.x, tid = threadIdx.x;
    __shared__ float l0[512];
    __shared__ float hh[256];
    l0[tid]       = silu_f(dec_f((unsigned)(argBuf2[(size_t)c * 512 + tid] >> 32)));
    l0[tid + 256] = silu_f(dec_f((unsigned)(argBuf2[(size_t)c * 512 + tid + 256] >> 32)));
    __syncthreads();
    float acc = b20[tid];
    for (int k = 0; k < 512; ++k) acc += l0[k] * W20[(size_t)k * 256 + tid];
    hh[tid] = silu_f(acc);
    __syncthreads();
    #pragma unroll
    for (int r = 0; r < 2; ++r) {
        int f = tid + r * 256;
        float a2 = b21[f];
        for (int k = 0; k < 256; ++k) a2 += hh[k] * W21[(size_t)k * 512 + f];
        latent[(size_t)c * 512 + f] = a2;
    }
}

// out[b][:] = latent[x[b]][:]
__global__ void k_scatter(const int* __restrict__ x,
                          const float* __restrict__ latent,
                          float* __restrict__ out)
{
    const int b = blockIdx.x, t = threadIdx.x;   // 128 threads, float4 each
    int cid = x[b];
    const float4* src = (const float4*)(latent + (size_t)cid * 512);
    float4* dst = (float4*)(out + (size_t)b * 512);
    dst[t] = src[t];
}

extern "C" void kernel_launch(void* const* d_in, const int* in_sizes, int n_in,
                              void* d_out, int out_size, void* d_ws, size_t ws_size,
                              hipStream_t stream)
{
    const float* pts = (const float*)d_in[0];
    const float* W10 = (const float*)d_in[1];
    const float* b10 = (const float*)d_in[2];
    const float* W11 = (const float*)d_in[3];
    const float* b11 = (const float*)d_in[4];
    const float* W12 = (const float*)d_in[5];
    const float* b12 = (const float*)d_in[6];
    const float* W20 = (const float*)d_in[7];
    const float* b20 = (const float*)d_in[8];
    const float* W21 = (const float*)d_in[9];
    const float* b21 = (const float*)d_in[10];
    const int*   x   = (const int*)d_in[11];
    float* out = (float*)d_out;

    // Workspace layout (re-poisoned every call -> rebuild every call):
    char* ws = (char*)d_ws;
    unsigned long long* argBuf  = (unsigned long long*)ws;              //  64 KB
    unsigned long long* argBuf2 = (unsigned long long*)(ws + 65536);    //  64 KB
    float* latent               = (float*)(ws + 131072);                //  32 KB
    ush* BbWs                   = (ush*)(ws + 163840);                  //  16 KB
    ush* BcWs                   = (ush*)(ws + 180224);                  // 128 KB (total 308 KB)

    // prep: swizzle weights to MFMA B-frag order + zero both argmax buffers
    k_prep<<<dim3(256), dim3(256), 0, stream>>>(W11, W12, BbWs, BcWs, argBuf);

    // Phase 1: big MLP + argmax over 65536 points/case
    k_mlp1_argmax<false><<<dim3(128, NCASES), dim3(512), 0, stream>>>(
        pts, NPTS_BIG, 8, nullptr, W10, b10, b11, b12, BbWs, BcWs, argBuf);

    // Phase 2+3 fused: MLP over 512 critical points/case (gather via argBuf) + max
    k_mlp1_argmax<true><<<dim3(8, NCASES), dim3(512), 0, stream>>>(
        pts, NPTS_BIG, 1, argBuf, W10, b10, b11, b12, BbWs, BcWs, argBuf2);

    // Phase 4: head MLP per case (applies silu to decoded max)
    k_head<<<dim3(NCASES), dim3(256), 0, stream>>>(argBuf2, W20, b20, W21, b21, latent);

    // Phase 5: scatter latent rows to output by case id
    k_scatter<<<dim3(OUT_B), dim3(128), 0, stream>>>(x, latent, out);
}

// Round 7
// 313.589 us; speedup vs baseline: 1.1005x; 1.1005x over previous
//
#include <hip/hip_runtime.h>
#include <math.h>

// Problem constants
#define NCASES   16
#define NPTS_BIG 65536
#define F1       512
#define OUT_B    4096

typedef __attribute__((ext_vector_type(8))) short  short8;   // 8 bf16 = 4 VGPR (MFMA A/B frag)
typedef __attribute__((ext_vector_type(4))) float  floatx4;  // MFMA C/D frag
typedef unsigned short ush;

__device__ __forceinline__ float silu_f(float x) {
    return x * __builtin_amdgcn_rcpf(1.0f + __expf(-x));
}

// RNE fp32->bf16 left in bits [31:16]  (used in one-time prep only)
__device__ __forceinline__ unsigned f2bf_hi(float x) {
    unsigned u = __float_as_uint(x);
    return u + 0x7FFFu + ((u >> 16) & 1u);
}
__device__ __forceinline__ ush f2bf(float x) {
    return (ush)(f2bf_hi(x) >> 16);
}
// RTZ pack: two f32 -> two bf16 in one v_perm (truncate mantissa; hot-loop path).
__device__ __forceinline__ unsigned pk2bf_rtz(float lo, float hi) {
    return __builtin_amdgcn_perm(__float_as_uint(hi), __float_as_uint(lo), 0x07060302u);
}

// Monotone float -> uint mapping (handles negatives) for atomicMax argmax.
__device__ __forceinline__ unsigned enc_f(float x) {
    unsigned u = __float_as_uint(x);
    return (u & 0x80000000u) ? ~u : (u | 0x80000000u);
}
__device__ __forceinline__ float dec_f(unsigned e) {
    unsigned u = (e & 0x80000000u) ? (e ^ 0x80000000u) : ~e;
    return __uint_as_float(u);
}

// force value to SGPR
__device__ __forceinline__ float sgpr_f(float x) {
    return __uint_as_float(__builtin_amdgcn_readfirstlane(__float_as_uint(x)));
}

// Pre-swizzle W11/W12 into MFMA B-fragment order (bf16, RNE) + zero argmax
// buffers AND the per-case done-counters (entries 16384..16399).
// B-layout for 16x16x32: B[k = KT*32 + (lane>>4)*8 + j][n = lane&15].
// BcWs: [w(8)][NT(4)][KT(4)][lane(64)][j(8)]  (W12, 128 KB)
// BbWs: [w(8)][KT(2)][lane(64)][j(8)]         (W11, 16 KB)
__global__ void k_prep(const float* __restrict__ W11, const float* __restrict__ W12,
                       ush* __restrict__ BbWs, ush* __restrict__ BcWs,
                       unsigned long long* __restrict__ argBufs)
{
    int i = blockIdx.x * 256 + threadIdx.x;   // 65536 threads
    if (i < 16400) argBufs[i] = 0ull;         // argBuf + argBuf2 + doneCnt
    {
        int j = i & 7, l = (i >> 3) & 63, t = i >> 9;     // t = w*16 + NT*4 + KT
        int KT = t & 3, NT = (t >> 2) & 3, w = t >> 4;
        int k = KT * 32 + (l >> 4) * 8 + j;
        int f = w * 64 + NT * 16 + (l & 15);
        BcWs[i] = f2bf(W12[(size_t)k * 512 + f]);
    }
    if (i < 8192) {
        int j = i & 7, l = (i >> 3) & 63, t = i >> 9;     // t = w*2 + KT
        int KT = t & 1, w = t >> 1;
        int k = KT * 32 + (l >> 4) * 8 + j;
        int f = w * 16 + (l & 15);
        BbWs[i] = f2bf(W11[(size_t)k * 128 + f]);
    }
}

// Fused mlp1 + per-feature argmax of PRE-ACTIVATION (silu monotone for x>=-1.278,
// silu(x)<0 for x<0, per-feature max pre-act > 0 w.o.p. -> argmax silu(z) == argmax z).
// b12 added after the max; silu applied downstream.
//
// PIPELINE (R1 structure -- best measured across R1..R6 variants):
// double-buffered h0/h1, ONE barrier per chunk:
//   [B(ch): h0[p]->h1[p];  A(ch+1): ->h0[p^1];  barrier;  C(ch): h1[p]]
// Settled findings: SQ_LDS_BANK_CONFLICT here is inherent b128 access-splitting
// (R2); jamming C||B||A is neutral, full-unroll jam spills Bc (R3/R4);
// 6 waves/SIMD needs <=85 regs and the live set doesn't fit -> spill (R6).
// Phase-1 wall ~= latency-bound at 4 waves/SIMD with pipes at 42/27/~42%.
//
// GATHER=true (phase 2) additionally fuses head MLP + output scatter into the
// LAST block per case (device-scope done-counter handshake): kills the k_head
// and k_scatter launches.  Tail LDS lives only in this instantiation.
// LDS 53.2 KB (phase-1) -> 2 blocks/CU.  __launch_bounds__(512,4): regs <= 128.
template<bool GATHER>
__global__ __launch_bounds__(512, 4)
void k_mlp1_argmax(const float* __restrict__ pts, int nPts, int chunksPerBlock,
                   const unsigned long long* __restrict__ gatherIdx,
                   const float* __restrict__ W10, const float* __restrict__ b10,
                   const float* __restrict__ b11, const float* __restrict__ b12,
                   const ush* __restrict__ BbWs,
                   const ush* __restrict__ BcWs,
                   unsigned long long* __restrict__ argOut,
                   const float* __restrict__ W20, const float* __restrict__ b20,
                   const float* __restrict__ W21, const float* __restrict__ b21,
                   const int* __restrict__ x, float* __restrict__ out,
                   unsigned long long* __restrict__ doneCnt)
{
    const int c   = blockIdx.y;
    const int tid = threadIdx.x;
    const int w   = tid >> 6;   // wave 0..7
    const int l   = tid & 63;   // lane
    const int lm  = l & 15;     // m/n within 16x16 tile
    const int q   = l >> 4;     // quad

    __shared__ __align__(16) ush s_h0[2][64][72];   // bf16, stride 144B, dbuf
    __shared__ __align__(16) ush s_h1[2][64][136];  // bf16, stride 272B, dbuf

    const int wf = __builtin_amdgcn_readfirstlane(w);   // wave-uniform

    // stage-A weights in SGPRs (no LDS, no per-chunk reloads)
    float wA0[8], wA1[8], wA2[8], bA[8];
    #pragma unroll
    for (int j = 0; j < 8; ++j) {
        wA0[j] = sgpr_f(W10[  0 + wf * 8 + j]);
        wA1[j] = sgpr_f(W10[ 64 + wf * 8 + j]);
        wA2[j] = sgpr_f(W10[128 + wf * 8 + j]);
        bA[j]  = sgpr_f(b10[       wf * 8 + j]);
    }

    // persistent B fragments (AGPR side of the unified file)
    short8 Bc[16];   // [NT*4+KT] for W12 slice
    #pragma unroll
    for (int t = 0; t < 16; ++t)
        Bc[t] = *(const short8*)(BcWs + (size_t)((wf * 16 + t) * 64 + l) * 8);
    short8 Bb[2];    // [KT] for W11 slice
    #pragma unroll
    for (int t = 0; t < 2; ++t)
        Bb[t] = *(const short8*)(BbWs + (size_t)((wf * 2 + t) * 64 + l) * 8);

    const float bias11 = b11[wf * 16 + lm];
    const floatx4 bias4 = {bias11, bias11, bias11, bias11};
    const floatx4 zero4 = {0.f, 0.f, 0.f, 0.f};

    float bestv[4];
    #pragma unroll
    for (int NT = 0; NT < 4; ++NT) bestv[NT] = -INFINITY;

    const float* cpts = pts + (size_t)c * nPts * 3;

    // ---- helpers ----
    auto ldpt = [&](int ch, float& xx, float& yy, float& zz) {
        const int pbase = (blockIdx.x * chunksPerBlock + ch) * 64;
        if (GATHER) {
            unsigned gi = ~(unsigned)(gatherIdx[(size_t)c * 512 + pbase + l] & 0xFFFFFFFFull);
            const float* sp = cpts + (size_t)gi * 3;
            xx = sp[0]; yy = sp[1]; zz = sp[2];
        } else {
            const float* sp = cpts + (size_t)(pbase + l) * 3;
            xx = sp[0]; yy = sp[1]; zz = sp[2];
        }
    };
    // stage A: h0[p][64][64] = silu(pts @ W10 + b10); lane = point, wave = 8 feats
    auto stageA = [&](int p, float xx, float yy, float zz) {
        float v[8];
        #pragma unroll
        for (int j = 0; j < 8; ++j) {
            float t = fmaf(zz, wA2[j], bA[j]);
            t = fmaf(yy, wA1[j], t);
            t = fmaf(xx, wA0[j], t);
            v[j] = silu_f(t);
        }
        uint4 hv = { pk2bf_rtz(v[0], v[1]), pk2bf_rtz(v[2], v[3]),
                     pk2bf_rtz(v[4], v[5]), pk2bf_rtz(v[6], v[7]) };
        *(uint4*)&s_h0[p][l][wf * 8] = hv;   // 16B aligned
    };

    // ---- prologue: A(0) ----
    {
        float xx, yy, zz;
        ldpt(0, xx, yy, zz);
        stageA(0, xx, yy, zz);
    }
    __syncthreads();

    for (int ch = 0; ch < chunksPerBlock; ++ch) {
        const int p = ch & 1;
        const bool more = (ch + 1 < chunksPerBlock);

        // issue next chunk's point loads early (hide under stage-B MFMAs)
        float nx, ny, nz;
        if (more) ldpt(ch + 1, nx, ny, nz);

        // ---- stage B: h1[p][64][128] = silu(h0[p] @ W11 + b11); bias as MFMA C-init ----
        #pragma unroll
        for (int MT = 0; MT < 4; ++MT) {
            short8 a0 = *(const short8*)&s_h0[p][MT * 16 + lm][q * 8];        // A[m=lm][k=q*8+j]
            short8 a1 = *(const short8*)&s_h0[p][MT * 16 + lm][32 + q * 8];
            floatx4 acc = __builtin_amdgcn_mfma_f32_16x16x32_bf16(a0, Bb[0], bias4, 0, 0, 0);
            acc = __builtin_amdgcn_mfma_f32_16x16x32_bf16(a1, Bb[1], acc, 0, 0, 0);
            #pragma unroll
            for (int r = 0; r < 4; ++r) {  // C/D: row = q*4+r (point), col = lm (feature)
                unsigned uv = __float_as_uint(silu_f(acc[r]));   // RTZ bf16: raw hi-half
                s_h1[p][MT * 16 + q * 4 + r][wf * 16 + lm] = (ush)(uv >> 16);
            }
        }

        // ---- stage A for chunk ch+1 into the other h0 buffer ----
        if (more) stageA(p ^ 1, nx, ny, nz);

        __syncthreads();   // h1[p] ready for C(ch); h0[p^1] ready for B(ch+1)

        // ---- stage C: pre-act feats = h1[p] @ W12; code-in-mantissa max3 argmax ----
        const int cb0 = 127 - (ch << 4);
        #pragma unroll
        for (int MT = 0; MT < 4; ++MT) {
            short8 a[4];
            #pragma unroll
            for (int KT = 0; KT < 4; ++KT)
                a[KT] = *(const short8*)&s_h1[p][MT * 16 + lm][KT * 32 + q * 8];
            const int cbM = cb0 - (MT << 2);
            #pragma unroll
            for (int NT = 0; NT < 4; ++NT) {
                floatx4 acc = __builtin_amdgcn_mfma_f32_16x16x32_bf16(a[0], Bc[NT * 4 + 0], zero4, 0, 0, 0);
                #pragma unroll
                for (int KT = 1; KT < 4; ++KT)
                    acc = __builtin_amdgcn_mfma_f32_16x16x32_bf16(a[KT], Bc[NT * 4 + KT], acc, 0, 0, 0);
                float x0 = __uint_as_float((__float_as_uint(acc[0]) & 0xFFFFFF80u) | (unsigned)(cbM));
                float x1 = __uint_as_float((__float_as_uint(acc[1]) & 0xFFFFFF80u) | (unsigned)(cbM - 1));
                float x2 = __uint_as_float((__float_as_uint(acc[2]) & 0xFFFFFF80u) | (unsigned)(cbM - 2));
                float x3 = __uint_as_float((__float_as_uint(acc[3]) & 0xFFFFFF80u) | (unsigned)(cbM - 3));
                float t0 = fmaxf(fmaxf(x0, x1), x2);
                bestv[NT] = fmaxf(fmaxf(t0, x3), bestv[NT]);
            }
        }
    }

    // ---- flush: decode code, strip it, combine quads via shfl, add b12, atomicMax ----
    #pragma unroll
    for (int NT = 0; NT < 4; ++NT) {
        unsigned u = __float_as_uint(bestv[NT]);
        int t = 127 - (int)(u & 127u);            // = ch<<4 | MT<<2 | r  (exact)
        unsigned idx = (unsigned)((blockIdx.x * chunksPerBlock + (t >> 4)) * 64
                                  + ((t >> 2) & 3) * 16 + q * 4 + (t & 3));
        float v = __uint_as_float(u & 0xFFFFFF80u) + b12[wf * 64 + NT * 16 + lm];
        #pragma unroll
        for (int m = 16; m <= 32; m <<= 1) {
            float    vo = __shfl_xor(v, m, 64);
            unsigned io = __shfl_xor(idx, m, 64);
            if (vo > v || (vo == v && io < idx)) { v = vo; idx = io; }
        }
        if (q == 0) {
            unsigned long long key = ((unsigned long long)enc_f(v) << 32)
                                   | (unsigned long long)(~idx);
            atomicMax(&argOut[(size_t)c * 512 + wf * 64 + NT * 16 + lm], key);
        }
    }

    // ---- GATHER only: last block per case runs head MLP + output scatter ----
    if constexpr (GATHER) {
        __threadfence();                       // release: flush atomics visible
        __syncthreads();
        __shared__ unsigned long long s_old;
        if (tid == 0) s_old = atomicAdd(&doneCnt[c], 1ull);
        __syncthreads();
        if (s_old == 7ull) {                   // all 8 blocks of this case done
            __threadfence();                   // acquire side
            __shared__ float s_l0[512];
            __shared__ float s_part[2][256];
            __shared__ float s_hh[256];
            __shared__ int   s_list[4096];
            __shared__ int   s_n;
            // latent0 = silu(decoded max pre-act); atomic read-back for coherence
            unsigned long long key = atomicMax(&argOut[(size_t)c * 512 + tid], 0ull);
            s_l0[tid] = silu_f(dec_f((unsigned)(key >> 32)));
            if (tid == 0) s_n = 0;
            __syncthreads();
            // head layer 1 (split-k over 2 halves): hh = silu(l0 @ W20 + b20)
            {
                const int h = tid & 255, half = tid >> 8;
                const float* wcol = W20 + (size_t)(half * 256) * 256 + h;
                const float* lv   = s_l0 + half * 256;
                float acc = 0.f;
                #pragma unroll 4
                for (int k = 0; k < 256; ++k)
                    acc = fmaf(lv[k], wcol[(size_t)k * 256], acc);
                s_part[half][h] = acc;
            }
            __syncthreads();
            if (tid < 256)
                s_hh[tid] = silu_f(s_part[0][tid] + s_part[1][tid] + b20[tid]);
            __syncthreads();
            // head layer 2: lat[tid] = b21 + hh @ W21  (kept in register)
            float lat = b21[tid];
            #pragma unroll 4
            for (int k = 0; k < 256; ++k)
                lat = fmaf(s_hh[k], W21[(size_t)k * 512 + tid], lat);
            // build list of output rows with x[b]==c, then coalesced row writes
            #pragma unroll
            for (int r = 0; r < 8; ++r) {
                int b = r * 512 + tid;
                if (x[b] == c) { int pos = atomicAdd(&s_n, 1); s_list[pos] = b; }
            }
            __syncthreads();
            const int n = s_n;
            for (int i = 0; i < n; ++i)
                out[(size_t)s_list[i] * 512 + tid] = lat;
        }
    }
}

extern "C" void kernel_launch(void* const* d_in, const int* in_sizes, int n_in,
                              void* d_out, int out_size, void* d_ws, size_t ws_size,
                              hipStream_t stream)
{
    const float* pts = (const float*)d_in[0];
    const float* W10 = (const float*)d_in[1];
    const float* b10 = (const float*)d_in[2];
    const float* W11 = (const float*)d_in[3];
    const float* b11 = (const float*)d_in[4];
    const float* W12 = (const float*)d_in[5];
    const float* b12 = (const float*)d_in[6];
    const float* W20 = (const float*)d_in[7];
    const float* b20 = (const float*)d_in[8];
    const float* W21 = (const float*)d_in[9];
    const float* b21 = (const float*)d_in[10];
    const int*   x   = (const int*)d_in[11];
    float* out = (float*)d_out;

    // Workspace layout (re-poisoned every call -> rebuild every call):
    char* ws = (char*)d_ws;
    unsigned long long* argBuf  = (unsigned long long*)ws;              //  64 KB
    unsigned long long* argBuf2 = (unsigned long long*)(ws + 65536);    //  64 KB
    unsigned long long* doneCnt = (unsigned long long*)(ws + 131072);   // 128 B
    ush* BbWs                   = (ush*)(ws + 131200);                  //  16 KB
    ush* BcWs                   = (ush*)(ws + 147584);                  // 128 KB (total ~272 KB)

    // prep: swizzle weights to MFMA B-frag order + zero argmax buffers & counters
    k_prep<<<dim3(256), dim3(256), 0, stream>>>(W11, W12, BbWs, BcWs, argBuf);

    // Phase 1: big MLP + argmax over 65536 points/case
    k_mlp1_argmax<false><<<dim3(128, NCASES), dim3(512), 0, stream>>>(
        pts, NPTS_BIG, 8, nullptr, W10, b10, b11, b12, BbWs, BcWs, argBuf,
        nullptr, nullptr, nullptr, nullptr, nullptr, nullptr, nullptr);

    // Phase 2+3+4+5 fused: gathered mlp1 + cross-block max (atomicMax) +
    // last-block-per-case head MLP + output scatter
    k_mlp1_argmax<true><<<dim3(8, NCASES), dim3(512), 0, stream>>>(
        pts, NPTS_BIG, 1, argBuf, W10, b10, b11, b12, BbWs, BcWs, argBuf2,
        W20, b20, W21, b21, x, out, doneCnt);
}